// Round 5
// baseline (188.153 us; speedup 1.0000x reference)
//
#include <hip/hip_runtime.h>

#define THREADS 1024
#define PPT 16                        // points per thread
#define CPB (THREADS * PPT)           // 16384 points per block
#define NCHUNK 4                      // chunks per batch (3 full + 848 tail)
#define NBANDS 16
#define BAND_F (32 * 512)             // 32 rows * 512 cols = 16384 floats = 64 KB

// B=64, P=50000, H=W=512.
// 256 blocks = 1 per CU; 32 blocks per XCD handle that XCD's 8 batches.
// Image is consumed band-by-band via LDS staging: coalesced float4 streams
// replace random global gathers (TA/L2 random-line wall at ~5.5 cyc/lane).
__global__ __launch_bounds__(THREADS, 4) void rdc_kernel(
    const float* __restrict__ x,
    const int*   __restrict__ xA,
    const int*   __restrict__ yA,
    const int*   __restrict__ xB,
    const int*   __restrict__ yB,
    const float* __restrict__ gt,
    float* __restrict__ out,
    float inv_n)
{
    __shared__ float band[BAND_F];            // 64 KB
    __shared__ float wsum[THREADS / 64];

    const int tid = threadIdx.x;
    // Physical mapping: consecutive block ids round-robin across 8 XCDs.
    const int xcd = blockIdx.x & 7;
    const int w   = blockIdx.x >> 3;          // 0..31 within XCD
    const int bl  = w >> 2;                   // local batch 0..7
    const int ch  = w & 3;                    // chunk 0..3
    const int b   = xcd * 8 + bl;             // global batch
    const int base = ch * CPB;                // point offset within batch
    const int cnt  = min(CPB, 50000 - base);  // 16384 or 848

    const size_t pbase = (size_t)b * 50000 + base;

    // Phase 1: load this block's points into registers (coalesced, read-once).
    unsigned pa[PPT], pb[PPT];
    float g[PPT], zA[PPT], zB[PPT];
    #pragma unroll
    for (int k = 0; k < PPT; ++k) {
        const int s = k * THREADS + tid;
        if (s < cnt) {
            const size_t p = pbase + s;
            const int xa_ = __builtin_nontemporal_load(xA + p);
            const int ya_ = __builtin_nontemporal_load(yA + p);
            const int xb_ = __builtin_nontemporal_load(xB + p);
            const int yb_ = __builtin_nontemporal_load(yB + p);
            g[k]  = __builtin_nontemporal_load(gt + p);
            pa[k] = (unsigned)((ya_ << 9) | xa_);   // flat offset, 18 bits
            pb[k] = (unsigned)((yb_ << 9) | xb_);
        } else {
            // Sentinel: band id = 0x3FFFF never matches 0..15; g=0 -> loss 0.
            pa[k] = 0xFFFFFFFFu; pb[k] = 0xFFFFFFFFu; g[k] = 0.0f;
        }
        zA[k] = 0.0f; zB[k] = 0.0f;
    }

    const float4* __restrict__ img4 = (const float4*)(x + (size_t)b * (512 * 512));

    // Phase 2: stream image bands through LDS; resolve matching endpoints.
    for (int bi = 0; bi < NBANDS; ++bi) {
        __syncthreads();                       // previous band's reads done
        float4* dst4 = (float4*)band;
        #pragma unroll
        for (int j = 0; j < BAND_F / 4 / THREADS; ++j)   // 4 float4 per thread
            dst4[j * THREADS + tid] = img4[bi * (BAND_F / 4) + j * THREADS + tid];
        __syncthreads();
        #pragma unroll
        for (int k = 0; k < PPT; ++k) {
            if ((pa[k] >> 14) == (unsigned)bi) zA[k] = band[pa[k] & 16383];
            if ((pb[k] >> 14) == (unsigned)bi) zB[k] = band[pb[k] & 16383];
        }
    }

    // Phase 3: loss from register-resident z values.
    float acc = 0.0f;
    #pragma unroll
    for (int k = 0; k < PPT; ++k) {
        const float d = zA[k] - zB[k];
        const float t = -g[k] * d;
        // stable softplus: log1p(exp(t)) = max(t,0) + log1p(exp(-|t|))
        const float sp = fmaxf(t, 0.0f) + log1pf(__expf(-fabsf(t)));
        const float m  = fabsf(g[k]);          // 0 or 1
        acc += m * sp + (1.0f - m) * d * d;    // invalid slots contribute 0
    }

    // wave64 reduce + block reduce + one atomic per block
    #pragma unroll
    for (int off = 32; off > 0; off >>= 1)
        acc += __shfl_down(acc, off, 64);
    const int lane = tid & 63, wid = tid >> 6;
    if (lane == 0) wsum[wid] = acc;
    __syncthreads();
    if (tid == 0) {
        float s = 0.0f;
        #pragma unroll
        for (int i = 0; i < THREADS / 64; ++i) s += wsum[i];
        atomicAdd(out, s * inv_n);
    }
}

extern "C" void kernel_launch(void* const* d_in, const int* in_sizes, int n_in,
                              void* d_out, int out_size, void* d_ws, size_t ws_size,
                              hipStream_t stream) {
    const float* x  = (const float*)d_in[0];
    const int*   xA = (const int*)d_in[1];
    const int*   yA = (const int*)d_in[2];
    const int*   xB = (const int*)d_in[3];
    const int*   yB = (const int*)d_in[4];
    const float* gt = (const float*)d_in[5];
    float* out = (float*)d_out;

    const int n = in_sizes[1];                 // B*P = 3,200,000
    const float inv_n = 1.0f / (float)n;

    hipMemsetAsync(out, 0, sizeof(float), stream);
    rdc_kernel<<<64 * NCHUNK, THREADS, 0, stream>>>(x, xA, yA, xB, yB, gt, out, inv_n);
}